// Round 3
// baseline (339.533 us; speedup 1.0000x reference)
//
#include <hip/hip_runtime.h>

// Problem constants (match reference)
constexpr int B = 4;
constexpr int L = 4096;          // power of two (row & (L-1) works)
constexpr int H = 2048;
constexpr float EPS = 1e-5f;

constexpr int H4 = H / 4;        // 512 float4 groups per row
constexpr int THREADS = 256;
constexpr int WPB = THREADS / 64;        // 4 waves per block, 1 row per wave
constexpr int NROWS = B * L;             // 16384 rows
constexpr int GRID = NROWS / WPB;        // 4096 blocks
constexpr int NXCD = 8;
constexpr int CHUNK = GRID / NXCD;       // 512

__global__ __launch_bounds__(THREADS, 4)
void fused_conv_res_ln(const float4* __restrict__ x4,
                       const float4* __restrict__ w4,   // w4[c] = 4 taps of channel c
                       const float4* __restrict__ g4,
                       const float4* __restrict__ bt4,
                       float4* __restrict__ o4)
{
    // XCD-chunked bijective swizzle: consecutive rows (which share the conv
    // halo) land on the same XCD's L2. GRID (4096) divisible by NXCD (8).
    const int bid     = blockIdx.x;
    const int logical = (bid & (NXCD - 1)) * CHUNK + (bid >> 3);
    const int wave    = threadIdx.x >> 6;
    const int lane    = threadIdx.x & 63;

    const int row = logical * WPB + wave;    // 0 .. 16383 == b*L + l (contiguous)
    const int l   = row & (L - 1);

    const float4* xr   = x4 + (size_t)row * H4;   // this row's base
    float4*       orow = o4 + (size_t)row * H4;

    float4 y[8];
    float sum = 0.f, sq = 0.f;

    if (l >= 3) {
        // fast path: full 4-tap window in-bounds
        #pragma unroll
        for (int c = 0; c < 8; ++c) {
            const int j = lane + (c << 6);
            const float4 a0 = xr[j - 3 * H4];
            const float4 a1 = xr[j - 2 * H4];
            const float4 a2 = xr[j - 1 * H4];
            const float4 a3 = xr[j];
            const float4 w0 = w4[4 * j + 0];
            const float4 w1 = w4[4 * j + 1];
            const float4 w2 = w4[4 * j + 2];
            const float4 w3 = w4[4 * j + 3];
            float4 yy;
            yy.x = a0.x * w0.x + a1.x * w0.y + a2.x * w0.z + a3.x * w0.w + a3.x;
            yy.y = a0.y * w1.x + a1.y * w1.y + a2.y * w1.z + a3.y * w1.w + a3.y;
            yy.z = a0.z * w2.x + a1.z * w2.y + a2.z * w2.z + a3.z * w2.w + a3.z;
            yy.w = a0.w * w3.x + a1.w * w3.y + a2.w * w3.z + a3.w * w3.w + a3.w;
            y[c] = yy;
            sum += yy.x + yy.y + yy.z + yy.w;
            sq  += yy.x * yy.x + yy.y * yy.y + yy.z * yy.z + yy.w * yy.w;
        }
    } else {
        // first 3 rows of the batch: zero-pad missing taps (wave-uniform branch)
        const float4 z = make_float4(0.f, 0.f, 0.f, 0.f);
        #pragma unroll
        for (int c = 0; c < 8; ++c) {
            const int j = lane + (c << 6);
            const float4 a0 = z;                          // l < 3 always here
            const float4 a1 = (l >= 2) ? xr[j - 2 * H4] : z;
            const float4 a2 = (l >= 1) ? xr[j - 1 * H4] : z;
            const float4 a3 = xr[j];
            const float4 w0 = w4[4 * j + 0];
            const float4 w1 = w4[4 * j + 1];
            const float4 w2 = w4[4 * j + 2];
            const float4 w3 = w4[4 * j + 3];
            float4 yy;
            yy.x = a0.x * w0.x + a1.x * w0.y + a2.x * w0.z + a3.x * w0.w + a3.x;
            yy.y = a0.y * w1.x + a1.y * w1.y + a2.y * w1.z + a3.y * w1.w + a3.y;
            yy.z = a0.z * w2.x + a1.z * w2.y + a2.z * w2.z + a3.z * w2.w + a3.z;
            yy.w = a0.w * w3.x + a1.w * w3.y + a2.w * w3.z + a3.w * w3.w + a3.w;
            y[c] = yy;
            sum += yy.x + yy.y + yy.z + yy.w;
            sq  += yy.x * yy.x + yy.y * yy.y + yy.z * yy.z + yy.w * yy.w;
        }
    }

    // ---- wave-only reduction over the row (no LDS, no barrier) ----
    #pragma unroll
    for (int off = 1; off < 64; off <<= 1) {
        sum += __shfl_xor(sum, off, 64);
        sq  += __shfl_xor(sq,  off, 64);
    }

    const float inv_h = 1.0f / (float)H;
    const float mu    = sum * inv_h;
    const float var   = sq * inv_h - mu * mu;
    const float rstd  = rsqrtf(var + EPS);

    // ---- normalize + affine + store ----
    #pragma unroll
    for (int c = 0; c < 8; ++c) {
        const int j = lane + (c << 6);
        const float4 g  = g4[j];
        const float4 be = bt4[j];
        float4 o;
        o.x = (y[c].x - mu) * rstd * g.x + be.x;
        o.y = (y[c].y - mu) * rstd * g.y + be.y;
        o.z = (y[c].z - mu) * rstd * g.z + be.z;
        o.w = (y[c].w - mu) * rstd * g.w + be.w;
        orow[j] = o;
    }
}

extern "C" void kernel_launch(void* const* d_in, const int* in_sizes, int n_in,
                              void* d_out, int out_size, void* d_ws, size_t ws_size,
                              hipStream_t stream) {
    const float4* x     = (const float4*)d_in[0];
    const float4* w     = (const float4*)d_in[1];
    const float4* gamma = (const float4*)d_in[2];
    const float4* beta  = (const float4*)d_in[3];
    float4* out = (float4*)d_out;

    fused_conv_res_ln<<<dim3(GRID), dim3(THREADS), 0, stream>>>(x, w, gamma, beta, out);
}

// Round 4
// 247.476 us; speedup vs baseline: 1.3720x; 1.3720x over previous
//
#include <hip/hip_runtime.h>

// Problem constants (match reference)
constexpr int B = 4;
constexpr int L = 4096;
constexpr int H = 2048;
constexpr float EPS = 1e-5f;

constexpr int H4 = H / 4;              // 512 float4 groups per row
constexpr int THREADS = 256;
constexpr int COLS = H4 / THREADS;     // 2 float4 groups per thread
constexpr int ROWS = 8;                // rows (l values) per block
constexpr int TILES = (B * L) / ROWS;  // 2048 blocks
constexpr int TPB = L / ROWS;          // 512 tiles per batch
constexpr int NXCD = 8;
constexpr int WAVES = THREADS / 64;

__global__ __launch_bounds__(THREADS, 2)
void fused_conv_res_ln(const float4* __restrict__ x4,
                       const float4* __restrict__ w4,    // w4[c] = 4 taps of channel c
                       const float4* __restrict__ g4,
                       const float4* __restrict__ bt4,
                       float4* __restrict__ o4)
{
    // Bijective XCD-chunked swizzle: consecutive logical tiles (sharing the
    // 3-row halo) land on the same XCD's L2. TILES (2048) % NXCD (8) == 0.
    const int bid     = blockIdx.x;
    const int logical = (bid & (NXCD - 1)) * (TILES / NXCD) + (bid >> 3);
    const int b       = logical / TPB;
    const int tile    = logical - b * TPB;
    const int l0      = tile * ROWS;
    const int t       = threadIdx.x;
    const int wave    = t >> 6;
    const int lane    = t & 63;

    const size_t rowbase = (size_t)b * L;

    // ---- per-block constants: conv taps (gamma/beta deferred to phase 2) ----
    int    jj[COLS];
    float4 wc[COLS][4];
    #pragma unroll
    for (int c = 0; c < COLS; ++c) {
        jj[c] = t + c * THREADS;
        #pragma unroll
        for (int k = 0; k < 4; ++k) wc[c][k] = w4[4 * jj[c] + k];
    }

    // ---- sliding-window init: rows l0-3 .. l0 ----
    float4 xw[COLS][4];
    #pragma unroll
    for (int c = 0; c < COLS; ++c) {
        #pragma unroll
        for (int k = 0; k < 3; ++k) {
            const int lr = l0 - 3 + k;
            xw[c][k] = (lr >= 0) ? x4[(rowbase + lr) * H4 + jj[c]]
                                 : make_float4(0.f, 0.f, 0.f, 0.f);
        }
        xw[c][3] = x4[(rowbase + l0) * H4 + jj[c]];
    }

    __shared__ float s_sum[ROWS][WAVES];
    __shared__ float s_sq [ROWS][WAVES];

    // =========== PHASE 1: barrier-free conv over all 8 rows ===========
    float4 y[ROWS][COLS];

    #pragma unroll
    for (int r = 0; r < ROWS; ++r) {
        // issue next row's loads before this row's compute (MLP)
        float4 xn[COLS];
        if (r + 1 < ROWS) {
            #pragma unroll
            for (int c = 0; c < COLS; ++c)
                xn[c] = x4[(rowbase + l0 + r + 1) * H4 + jj[c]];
        }

        float sum = 0.f, sq = 0.f;
        #pragma unroll
        for (int c = 0; c < COLS; ++c) {
            const float4 a0 = xw[c][0], a1 = xw[c][1], a2 = xw[c][2], a3 = xw[c][3];
            float4 yy;
            yy.x = a0.x * wc[c][0].x + a1.x * wc[c][0].y + a2.x * wc[c][0].z + a3.x * wc[c][0].w + a3.x;
            yy.y = a0.y * wc[c][1].x + a1.y * wc[c][1].y + a2.y * wc[c][1].z + a3.y * wc[c][1].w + a3.y;
            yy.z = a0.z * wc[c][2].x + a1.z * wc[c][2].y + a2.z * wc[c][2].z + a3.z * wc[c][2].w + a3.z;
            yy.w = a0.w * wc[c][3].x + a1.w * wc[c][3].y + a2.w * wc[c][3].z + a3.w * wc[c][3].w + a3.w;
            y[r][c] = yy;
            sum += yy.x + yy.y + yy.z + yy.w;
            sq  += yy.x * yy.x + yy.y * yy.y + yy.z * yy.z + yy.w * yy.w;
        }

        // wave-level reduction only (no block rendezvous)
        #pragma unroll
        for (int off = 1; off < 64; off <<= 1) {
            sum += __shfl_xor(sum, off, 64);
            sq  += __shfl_xor(sq,  off, 64);
        }
        if (lane == 0) { s_sum[r][wave] = sum; s_sq[r][wave] = sq; }

        // slide window
        #pragma unroll
        for (int c = 0; c < COLS; ++c) {
            xw[c][0] = xw[c][1];
            xw[c][1] = xw[c][2];
            xw[c][2] = xw[c][3];
            if (r + 1 < ROWS) xw[c][3] = xn[c];
        }
    }

    __syncthreads();   // the ONLY barrier

    // =========== PHASE 2: finalize all 8 rows ===========
    float4 gg[COLS], bb[COLS];
    #pragma unroll
    for (int c = 0; c < COLS; ++c) { gg[c] = g4[jj[c]]; bb[c] = bt4[jj[c]]; }

    const float inv_h = 1.0f / (float)H;
    #pragma unroll
    for (int r = 0; r < ROWS; ++r) {
        float tot = 0.f, totq = 0.f;
        #pragma unroll
        for (int i = 0; i < WAVES; ++i) { tot += s_sum[r][i]; totq += s_sq[r][i]; }
        const float mu   = tot * inv_h;
        const float var  = totq * inv_h - mu * mu;
        const float rstd = rsqrtf(var + EPS);

        #pragma unroll
        for (int c = 0; c < COLS; ++c) {
            float4 o;
            o.x = (y[r][c].x - mu) * rstd * gg[c].x + bb[c].x;
            o.y = (y[r][c].y - mu) * rstd * gg[c].y + bb[c].y;
            o.z = (y[r][c].z - mu) * rstd * gg[c].z + bb[c].z;
            o.w = (y[r][c].w - mu) * rstd * gg[c].w + bb[c].w;
            o4[(rowbase + l0 + r) * H4 + jj[c]] = o;
        }
    }
}

extern "C" void kernel_launch(void* const* d_in, const int* in_sizes, int n_in,
                              void* d_out, int out_size, void* d_ws, size_t ws_size,
                              hipStream_t stream) {
    const float4* x     = (const float4*)d_in[0];
    const float4* w     = (const float4*)d_in[1];
    const float4* gamma = (const float4*)d_in[2];
    const float4* beta  = (const float4*)d_in[3];
    float4* out = (float4*)d_out;

    fused_conv_res_ln<<<dim3(TILES), dim3(THREADS), 0, stream>>>(x, w, gamma, beta, out);
}

// Round 5
// 243.506 us; speedup vs baseline: 1.3944x; 1.0163x over previous
//
#include <hip/hip_runtime.h>

// Problem constants (match reference)
constexpr int B = 4;
constexpr int L = 4096;
constexpr int H = 2048;
constexpr float EPS = 1e-5f;

constexpr int H4 = H / 4;              // 512 float4 groups per row
constexpr int THREADS = 256;
constexpr int COLS = H4 / THREADS;     // 2 float4 groups per thread
constexpr int ROWS = 8;                // rows (l values) per block
constexpr int TILES = (B * L) / ROWS;  // 2048 blocks
constexpr int TPB = L / ROWS;          // 512 tiles per batch
constexpr int NXCD = 8;
constexpr int WAVES = THREADS / 64;
constexpr int HALVES = WAVES * 2;      // half-wave partial slots per row

__global__ __launch_bounds__(THREADS, 2)
void fused_conv_res_ln(const float4* __restrict__ x4,
                       const float4* __restrict__ w4,    // w4[c] = 4 taps of channel c
                       const float4* __restrict__ g4,
                       const float4* __restrict__ bt4,
                       float4* __restrict__ o4)
{
    // Bijective XCD-chunked swizzle: consecutive logical tiles (sharing the
    // 3-row halo) land on the same XCD's L2. TILES (2048) % NXCD (8) == 0.
    const int bid     = blockIdx.x;
    const int logical = (bid & (NXCD - 1)) * (TILES / NXCD) + (bid >> 3);
    const int b       = logical / TPB;
    const int tile    = logical - b * TPB;
    const int l0      = tile * ROWS;
    const int t       = threadIdx.x;
    const int wave    = t >> 6;
    const int lane    = t & 63;

    const size_t rowbase = (size_t)b * L;

    // ---- per-block constants: conv taps ----
    int    jj[COLS];
    float4 wc[COLS][4];
    #pragma unroll
    for (int c = 0; c < COLS; ++c) {
        jj[c] = t + c * THREADS;
        #pragma unroll
        for (int k = 0; k < 4; ++k) wc[c][k] = w4[4 * jj[c] + k];
    }

    // ---- sliding-window init: rows l0-3 .. l0 ----
    float4 xw[COLS][4];
    #pragma unroll
    for (int c = 0; c < COLS; ++c) {
        #pragma unroll
        for (int k = 0; k < 3; ++k) {
            const int lr = l0 - 3 + k;
            xw[c][k] = (lr >= 0) ? x4[(rowbase + lr) * H4 + jj[c]]
                                 : make_float4(0.f, 0.f, 0.f, 0.f);
        }
        xw[c][3] = x4[(rowbase + l0) * H4 + jj[c]];
    }

    __shared__ float s_sum[ROWS][HALVES];
    __shared__ float s_sq [ROWS][HALVES];

    // =========== PHASE 1: pure load/VALU conv over all 8 rows ===========
    // No cross-lane ops in this loop -> load stream never stalls on LDS latency.
    float4 y[ROWS][COLS];
    float  s[ROWS], q[ROWS];

    #pragma unroll
    for (int r = 0; r < ROWS; ++r) {
        float4 xn[COLS];
        if (r + 1 < ROWS) {
            #pragma unroll
            for (int c = 0; c < COLS; ++c)
                xn[c] = x4[(rowbase + l0 + r + 1) * H4 + jj[c]];
        }

        float sum = 0.f, sq = 0.f;
        #pragma unroll
        for (int c = 0; c < COLS; ++c) {
            const float4 a0 = xw[c][0], a1 = xw[c][1], a2 = xw[c][2], a3 = xw[c][3];
            float4 yy;
            yy.x = a0.x * wc[c][0].x + a1.x * wc[c][0].y + a2.x * wc[c][0].z + a3.x * wc[c][0].w + a3.x;
            yy.y = a0.y * wc[c][1].x + a1.y * wc[c][1].y + a2.y * wc[c][1].z + a3.y * wc[c][1].w + a3.y;
            yy.z = a0.z * wc[c][2].x + a1.z * wc[c][2].y + a2.z * wc[c][2].z + a3.z * wc[c][2].w + a3.z;
            yy.w = a0.w * wc[c][3].x + a1.w * wc[c][3].y + a2.w * wc[c][3].z + a3.w * wc[c][3].w + a3.w;
            y[r][c] = yy;
            sum += yy.x + yy.y + yy.z + yy.w;
            sq  += yy.x * yy.x + yy.y * yy.y + yy.z * yy.z + yy.w * yy.w;
        }
        s[r] = sum; q[r] = sq;

        #pragma unroll
        for (int c = 0; c < COLS; ++c) {
            xw[c][0] = xw[c][1];
            xw[c][1] = xw[c][2];
            xw[c][2] = xw[c][3];
            if (r + 1 < ROWS) xw[c][3] = xn[c];
        }
    }

    // gamma/beta loads issued here so they overlap the reduction below
    float4 gg[COLS], bb[COLS];
    #pragma unroll
    for (int c = 0; c < COLS; ++c) { gg[c] = g4[jj[c]]; bb[c] = bt4[jj[c]]; }

    // =========== batched half-wave reduction: 16 independent chains ===========
    // 5 steps (offs 1..16); lane^32 step replaced by two half-wave LDS slots.
    #pragma unroll
    for (int off = 1; off < 32; off <<= 1) {
        #pragma unroll
        for (int r = 0; r < ROWS; ++r) {
            s[r] += __shfl_xor(s[r], off, 64);
            q[r] += __shfl_xor(q[r], off, 64);
        }
    }
    if ((lane & 31) == 0) {
        const int idx = wave * 2 + (lane >> 5);
        #pragma unroll
        for (int r = 0; r < ROWS; ++r) { s_sum[r][idx] = s[r]; s_sq[r][idx] = q[r]; }
    }

    __syncthreads();   // the ONLY barrier

    // =========== PHASE 2: finalize all 8 rows ===========
    const float inv_h = 1.0f / (float)H;
    #pragma unroll
    for (int r = 0; r < ROWS; ++r) {
        float tot = 0.f, totq = 0.f;
        #pragma unroll
        for (int i = 0; i < HALVES; ++i) { tot += s_sum[r][i]; totq += s_sq[r][i]; }
        const float mu   = tot * inv_h;
        const float var  = totq * inv_h - mu * mu;
        const float rstd = rsqrtf(var + EPS);

        #pragma unroll
        for (int c = 0; c < COLS; ++c) {
            float4 o;
            o.x = (y[r][c].x - mu) * rstd * gg[c].x + bb[c].x;
            o.y = (y[r][c].y - mu) * rstd * gg[c].y + bb[c].y;
            o.z = (y[r][c].z - mu) * rstd * gg[c].z + bb[c].z;
            o.w = (y[r][c].w - mu) * rstd * gg[c].w + bb[c].w;
            o4[(rowbase + l0 + r) * H4 + jj[c]] = o;
        }
    }
}

extern "C" void kernel_launch(void* const* d_in, const int* in_sizes, int n_in,
                              void* d_out, int out_size, void* d_ws, size_t ws_size,
                              hipStream_t stream) {
    const float4* x     = (const float4*)d_in[0];
    const float4* w     = (const float4*)d_in[1];
    const float4* gamma = (const float4*)d_in[2];
    const float4* beta  = (const float4*)d_in[3];
    float4* out = (float4*)d_out;

    fused_conv_res_ln<<<dim3(TILES), dim3(THREADS), 0, stream>>>(x, w, gamma, beta, out);
}